// Round 2
// baseline (291.136 us; speedup 1.0000x reference)
//
#include <hip/hip_runtime.h>

// PEG_Shift: depthwise 3x3 conv (stride 1, pad 1, groups=C) with
//   - weights rounded to signed powers of two (clamp |w| to [2^-14, 1])
//   - activations/bias in 16-bit fixed point (floor(x*2^16)*2^-16, clip)
// x: (32, 384, 56, 56) f32 -> out f32 same shape.
//
// R1 design: no LDS, no barriers. Sliding register window per thread.
//   - 16 lanes per (plane, half-plane): lanes 0..13 own 4-wide column strips,
//     lanes 14,15 idle. Strip boundaries align with shuffle predicates, so
//     __shfl_up/down for horizontal halo is always safe.
//   - Each lane: 28 output rows; holds quantized rows h-1,h,h+1 in regs,
//     prefetches raw row h+2 (1-iteration load-to-use distance).
//   - Vertical reuse in registers => each input element loaded once, qfix'd once.

#define DW_C   384
#define DW_H   56
#define DW_W   56
#define DW_HW  (DW_H * DW_W)   // 3136
#define HALF_H 28

__device__ __forceinline__ float qfix(float v) {
    v = floorf(v * 65536.0f) * (1.0f / 65536.0f);
    return fminf(fmaxf(v, -32768.0f), 32767.0f);
}

struct QRow { float l; float4 m; float r; };

__global__ __launch_bounds__(256) void peg_shift_dwconv(
    const float* __restrict__ x, const float* __restrict__ wgt,
    const float* __restrict__ bias, float* __restrict__ out)
{
    const int lane16 = threadIdx.x & 15;       // position within group
    const int g      = threadIdx.x >> 4;       // group 0..15 in block
    const int unit   = blockIdx.x * 16 + g;    // plane*2 + half
    const int plane  = unit >> 1;
    const int half   = unit & 1;
    const int c      = plane % DW_C;
    const int strip  = lane16;                 // 0..13 active
    const bool active = strip < 14;
    const int w0     = strip * 4;

    // ---- quantize 9 weights (power of two) + bias (fixed point); uniform per group ----
    float wq[9];
#pragma unroll
    for (int k = 0; k < 9; ++k) {
        float wv = wgt[c * 9 + k];
        float cw = fminf(fmaxf(fabsf(wv), 6.103515625e-05f /*2^-14*/), 1.0f);
        float q  = exp2f(rintf(log2f(cw)));    // rint = round-half-even = jnp.round
        wq[k] = (wv > 0.0f) ? q : ((wv < 0.0f) ? -q : 0.0f);
    }
    const float bq = qfix(bias[c]);

    const float* xp = x   + (size_t)plane * DW_HW + w0;
    float*       op = out + (size_t)plane * DW_HW + w0;
    const int h0 = half * HALF_H;

    auto load_row = [&](int r) -> float4 {
        if (active && r >= 0 && r < DW_H)
            return *(const float4*)(xp + r * DW_W);
        return make_float4(0.f, 0.f, 0.f, 0.f);
    };

    // quantize a raw row + fetch horizontal halo from neighbor lanes (already quantized)
    auto process = [&](float4 raw) -> QRow {
        QRow t;
        t.m.x = qfix(raw.x); t.m.y = qfix(raw.y);
        t.m.z = qfix(raw.z); t.m.w = qfix(raw.w);
        float up = __shfl_up(t.m.w, 1, 64);    // lane-1's last elem
        float dn = __shfl_down(t.m.x, 1, 64);  // lane+1's first elem
        t.l = (strip > 0)  ? up : 0.f;         // strip 0  -> left  zero-pad
        t.r = (strip < 13) ? dn : 0.f;         // strip 13 -> right zero-pad
        return t;
    };

    // ---- prologue: rows h0-1, h0 processed; row h0+1 raw in flight ----
    float4 ra   = load_row(h0 - 1);
    float4 rb   = load_row(h0);
    float4 rawc = load_row(h0 + 1);
    QRow qm1 = process(ra);
    QRow q0  = process(rb);

    // ---- main loop: compute output row h0+i from rows (h0+i-1, h0+i, h0+i+1) ----
    for (int i = 0; i < HALF_H; ++i) {
        float4 rawn = load_row(h0 + i + 2);    // prefetch, consumed next iter
        QRow q1 = process(rawc);

        float a0 = bq, a1 = bq, a2 = bq, a3 = bq;
        // row -1
        a0 += qm1.l   * wq[0] + qm1.m.x * wq[1] + qm1.m.y * wq[2];
        a1 += qm1.m.x * wq[0] + qm1.m.y * wq[1] + qm1.m.z * wq[2];
        a2 += qm1.m.y * wq[0] + qm1.m.z * wq[1] + qm1.m.w * wq[2];
        a3 += qm1.m.z * wq[0] + qm1.m.w * wq[1] + qm1.r   * wq[2];
        // row 0
        a0 += q0.l   * wq[3] + q0.m.x * wq[4] + q0.m.y * wq[5];
        a1 += q0.m.x * wq[3] + q0.m.y * wq[4] + q0.m.z * wq[5];
        a2 += q0.m.y * wq[3] + q0.m.z * wq[4] + q0.m.w * wq[5];
        a3 += q0.m.z * wq[3] + q0.m.w * wq[4] + q0.r   * wq[5];
        // row +1
        a0 += q1.l   * wq[6] + q1.m.x * wq[7] + q1.m.y * wq[8];
        a1 += q1.m.x * wq[6] + q1.m.y * wq[7] + q1.m.z * wq[8];
        a2 += q1.m.y * wq[6] + q1.m.z * wq[7] + q1.m.w * wq[8];
        a3 += q1.m.z * wq[6] + q1.m.w * wq[7] + q1.r   * wq[8];

        if (active) {
            float4 o; o.x = a0; o.y = a1; o.z = a2; o.w = a3;
            *(float4*)(op + (h0 + i) * DW_W) = o;
        }
        qm1 = q0; q0 = q1; rawc = rawn;
    }
}

extern "C" void kernel_launch(void* const* d_in, const int* in_sizes, int n_in,
                              void* d_out, int out_size, void* d_ws, size_t ws_size,
                              hipStream_t stream) {
    const float* x = (const float*)d_in[0];
    const float* w = (const float*)d_in[1];
    const float* b = (const float*)d_in[2];
    float* out = (float*)d_out;

    int planes = in_sizes[0] / DW_HW;           // 32*384 = 12288
    int blocks = planes * 2 / 16;               // 16 (plane,half) units per block
    peg_shift_dwconv<<<blocks, 256, 0, stream>>>(x, w, b, out);
}

// Round 3
// 275.138 us; speedup vs baseline: 1.0581x; 1.0581x over previous
//
#include <hip/hip_runtime.h>

// PEG_Shift: depthwise 3x3 conv (stride 1, pad 1, groups=C) with
//   - weights rounded to signed powers of two (clamp |w| to [2^-14, 1])
//   - activations/bias in 16-bit fixed point (floor(x*2^16)*2^-16, clip)
// x: (32, 384, 56, 56) f32 -> out f32 same shape.
//
// R2 design: one wave per plane, streaming 4 consecutive rows per iteration.
//   Lane = rg*16 + w4 : rg = row-in-group (0..3), w4 = 4-wide column strip
//   (0..13 active, 14..15 idle). Wave load/store = 896 B contiguous
//   = exactly 7 aligned 128B lines (no partial-line writes).
//   Conv reorganized as per-input-row partials:
//     pU = row's contribution to output row+1 (weights 0..2)
//     pM = contribution to own output row      (weights 3..5, + bias)
//     pD = contribution to output row-1        (weights 6..8)
//   out[r] = pU[r-1] + pM[r] + pD[r+1]  -> vertical halo via shfl +/-16,
//   cross-group via shfl +/-48. Two groups pipelined (2 loads in flight).

#define DW_C    384
#define DW_H    56
#define DW_W    56
#define DW_HW   (DW_H * DW_W)   // 3136
#define NGRP    14              // 56 rows / 4

__device__ __forceinline__ float qfix(float v) {
    v = floorf(v * 65536.0f) * (1.0f / 65536.0f);
    return fminf(fmaxf(v, -32768.0f), 32767.0f);
}

struct P3 { float4 U, M, D; };

__device__ __forceinline__ float4 shfl_up4(float4 v, int d) {
    float4 r;
    r.x = __shfl_up(v.x, d, 64); r.y = __shfl_up(v.y, d, 64);
    r.z = __shfl_up(v.z, d, 64); r.w = __shfl_up(v.w, d, 64);
    return r;
}
__device__ __forceinline__ float4 shfl_dn4(float4 v, int d) {
    float4 r;
    r.x = __shfl_down(v.x, d, 64); r.y = __shfl_down(v.y, d, 64);
    r.z = __shfl_down(v.z, d, 64); r.w = __shfl_down(v.w, d, 64);
    return r;
}

__global__ __launch_bounds__(256) void peg_shift_dwconv(
    const float* __restrict__ x, const float* __restrict__ wgt,
    const float* __restrict__ bias, float* __restrict__ out)
{
    const int lane  = threadIdx.x & 63;
    const int wave  = threadIdx.x >> 6;
    const int plane = blockIdx.x * 4 + wave;     // one plane per wave
    const int rg    = lane >> 4;                 // row in group, 0..3
    const int w4    = lane & 15;                 // strip, 0..13 active
    const bool active = w4 < 14;
    const int c     = plane % DW_C;

    // ---- quantize 9 weights (power of two) + bias (fixed point); wave-uniform ----
    float wq[9];
#pragma unroll
    for (int k = 0; k < 9; ++k) {
        float wv = wgt[c * 9 + k];
        float cw = fminf(fmaxf(fabsf(wv), 6.103515625e-05f /*2^-14*/), 1.0f);
        float q  = exp2f(rintf(log2f(cw)));      // round-half-even = jnp.round
        wq[k] = (wv > 0.0f) ? q : ((wv < 0.0f) ? -q : 0.0f);
    }
    const float bq = qfix(bias[c]);

    const int   lane_off = rg * DW_W + w4 * 4;   // within-plane float offset
    const float* xp = x   + (size_t)plane * DW_HW + lane_off;
    float*       op = out + (size_t)plane * DW_HW + lane_off;

    auto load_grp = [&](int g) -> float4 {       // rows 4g+rg, strip w4
        if (active) return *(const float4*)(xp + g * (4 * DW_W));
        return make_float4(0.f, 0.f, 0.f, 0.f);
    };

    // quantize one raw row-vec + build the 3 partial contribution vectors
    auto partials = [&](float4 raw) -> P3 {
        float4 m;
        m.x = qfix(raw.x); m.y = qfix(raw.y);
        m.z = qfix(raw.z); m.w = qfix(raw.w);
        float l = __shfl_up(m.w, 1, 64);   l = (w4 > 0)  ? l : 0.f;
        float r = __shfl_down(m.x, 1, 64); r = (w4 < 13) ? r : 0.f;
        P3 p;
        p.U.x = l*wq[0] + m.x*wq[1] + m.y*wq[2];
        p.U.y = m.x*wq[0] + m.y*wq[1] + m.z*wq[2];
        p.U.z = m.y*wq[0] + m.z*wq[1] + m.w*wq[2];
        p.U.w = m.z*wq[0] + m.w*wq[1] + r*wq[2];
        p.M.x = bq + l*wq[3] + m.x*wq[4] + m.y*wq[5];
        p.M.y = bq + m.x*wq[3] + m.y*wq[4] + m.z*wq[5];
        p.M.z = bq + m.y*wq[3] + m.z*wq[4] + m.w*wq[5];
        p.M.w = bq + m.z*wq[3] + m.w*wq[4] + r*wq[5];
        p.D.x = l*wq[6] + m.x*wq[7] + m.y*wq[8];
        p.D.y = m.x*wq[6] + m.y*wq[7] + m.z*wq[8];
        p.D.z = m.y*wq[6] + m.z*wq[7] + m.w*wq[8];
        p.D.w = m.z*wq[6] + m.w*wq[7] + r*wq[8];
        return p;
    };

    // ---- prologue: group 0 partials ready, group 1 raw in flight ----
    float4 raw0 = load_grp(0);
    float4 rawN = load_grp(1);
    P3 P0 = partials(raw0);
    float4 carryU = make_float4(0.f, 0.f, 0.f, 0.f);   // pU of row -1 (top pad)
    const float4 zero4 = make_float4(0.f, 0.f, 0.f, 0.f);

    for (int i = 0; i < NGRP; ++i) {
        float4 raw2 = (i + 2 < NGRP) ? load_grp(i + 2) : zero4;

        P3 P1;
        if (i + 1 < NGRP) P1 = partials(rawN);
        else              { P1.U = zero4; P1.M = zero4; P1.D = zero4; }  // row-56 pad

        // vertical halos for output rows 4i+rg
        float4 dn_cross = shfl_up4(P1.D, 48);          // next group's rg=0 pD -> rg=3 lanes
        float4 upS = shfl_up4(P0.U, 16);
        float4 dnS = shfl_dn4(P0.D, 16);
        float4 up, dn;
        up.x = (rg > 0) ? upS.x : carryU.x;  up.y = (rg > 0) ? upS.y : carryU.y;
        up.z = (rg > 0) ? upS.z : carryU.z;  up.w = (rg > 0) ? upS.w : carryU.w;
        dn.x = (rg < 3) ? dnS.x : dn_cross.x; dn.y = (rg < 3) ? dnS.y : dn_cross.y;
        dn.z = (rg < 3) ? dnS.z : dn_cross.z; dn.w = (rg < 3) ? dnS.w : dn_cross.w;

        if (active) {
            float4 o;
            o.x = up.x + P0.M.x + dn.x;
            o.y = up.y + P0.M.y + dn.y;
            o.z = up.z + P0.M.z + dn.z;
            o.w = up.w + P0.M.w + dn.w;
            *(float4*)(op + i * (4 * DW_W)) = o;
        }

        carryU = shfl_dn4(P0.U, 48);   // this group's rg=3 pU -> next iter's rg=0
        P0 = P1;
        rawN = raw2;
    }
}

extern "C" void kernel_launch(void* const* d_in, const int* in_sizes, int n_in,
                              void* d_out, int out_size, void* d_ws, size_t ws_size,
                              hipStream_t stream) {
    const float* x = (const float*)d_in[0];
    const float* w = (const float*)d_in[1];
    const float* b = (const float*)d_in[2];
    float* out = (float*)d_out;

    int planes = in_sizes[0] / DW_HW;            // 32*384 = 12288
    int blocks = planes / 4;                     // 4 waves (planes) per block
    peg_shift_dwconv<<<blocks, 256, 0, stream>>>(x, w, b, out);
}